// Round 2
// baseline (93.988 us; speedup 1.0000x reference)
//
#include <hip/hip_runtime.h>

#define NBINS 40
#define TLEN  200
#define NFEAT 42
#define H1    128
#define H2    64
#define NE    3

// One thread per sample, 256 threads/block, grid = B/256 = 256 blocks.
// Grid gives exactly 1 block/CU -> 1 wave/SIMD; occupancy is grid-limited,
// so pin waves_per_eu to 1 and let the allocator use ~200 VGPRs (no spills).
__global__ __launch_bounds__(256) __attribute__((amdgpu_waves_per_eu(1, 1)))
void gating_fused(const int* __restrict__ x,
                  const float* __restrict__ W1, const float* __restrict__ b1,
                  const float* __restrict__ W2, const float* __restrict__ b2,
                  const float* __restrict__ W3, const float* __restrict__ b3,
                  float* __restrict__ out)
{
    const int tid = threadIdx.x;
    const size_t b = (size_t)blockIdx.x * 256 + tid;

    // ---- register bitplane histogram: 8 planes x 64 bins (lo/hi u32) ----
    // counts <= 200 < 256 -> 8 planes. Carry-save ripple add of a one-hot.
    uint32_t plo[8], phi[8];
    #pragma unroll
    for (int p = 0; p < 8; ++p) { plo[p] = 0u; phi[p] = 0u; }

    const int4* xrow = reinterpret_cast<const int4*>(x + b * TLEN);
    // depth-4 software pipeline on the 16B token loads
    int4 q0 = xrow[0], q1 = xrow[1], q2 = xrow[2], q3 = xrow[3];
    for (int it = 0; it < TLEN / 4; ++it) {
        int4 cur = q0; q0 = q1; q1 = q2; q2 = q3;
        int nxt = it + 4; nxt = (nxt < TLEN / 4) ? nxt : (TLEN / 4 - 1);
        q3 = xrow[nxt];
        #pragma unroll
        for (int s = 0; s < 4; ++s) {
            const int t = (&cur.x)[s];           // s is compile-time (unrolled)
            const uint32_t sh  = 1u << (t & 31);
            uint32_t olo = (t != 0 && t < 32) ? sh : 0u;  // pad token 0 excluded
            uint32_t ohi = (t >= 32) ? sh : 0u;
            #pragma unroll
            for (int p = 0; p < 8; ++p) {
                const uint32_t cl = plo[p] & olo; plo[p] ^= olo; olo = cl;
                const uint32_t ch = phi[p] & ohi; phi[p] ^= ohi; ohi = ch;
            }
        }
    }

    // ---- extract features ----
    float f[NFEAT];
    uint32_t orv_lo = 0u, orv_hi = 0u;
    #pragma unroll
    for (int p = 0; p < 8; ++p) { orv_lo |= plo[p]; orv_hi |= phi[p]; }
    const uint32_t uniq = (uint32_t)(__popc(orv_lo) + __popc(orv_hi));

    uint32_t total = 0u;
    f[2 + 0] = 0.0f;                              // bin 0 never counted
    #pragma unroll
    for (int c = 1; c < 32; ++c) {
        uint32_t cnt = 0u;
        #pragma unroll
        for (int p = 7; p >= 0; --p) cnt = cnt * 2u + ((plo[p] >> c) & 1u);
        f[2 + c] = (float)cnt; total += cnt;
    }
    #pragma unroll
    for (int c = 32; c < NBINS; ++c) {
        uint32_t cnt = 0u;
        #pragma unroll
        for (int p = 7; p >= 0; --p) cnt = cnt * 2u + ((phi[p] >> (c - 32)) & 1u);
        f[2 + c] = (float)cnt; total += cnt;
    }
    f[0] = (float)total;                          // seq_len
    f[1] = (float)uniq;                           // unique_chars

    // ---- layer1 (42->128) chunked by 8, fused into layer2 (128->64) ----
    float acc2[H2];
    #pragma unroll
    for (int k = 0; k < H2; ++k) acc2[k] = b2[k];

    for (int jc = 0; jc < H1 / 8; ++jc) {         // wave-uniform weight indices
        float a[8];
        #pragma unroll
        for (int u = 0; u < 8; ++u) a[u] = b1[jc * 8 + u];
        #pragma unroll
        for (int i = 0; i < NFEAT; ++i) {
            const float fi = f[i];
            #pragma unroll
            for (int u = 0; u < 8; ++u)
                a[u] = fmaf(fi, W1[i * H1 + jc * 8 + u], a[u]);
        }
        #pragma unroll
        for (int u = 0; u < 8; ++u) {
            const float h = fmaxf(a[u], 0.0f);
            #pragma unroll
            for (int k = 0; k < H2; ++k)
                acc2[k] = fmaf(h, W2[(jc * 8 + u) * H2 + k], acc2[k]);
        }
    }

    // ---- layer3 (64->3) + softmax ----
    float lg[NE];
    #pragma unroll
    for (int e = 0; e < NE; ++e) lg[e] = b3[e];
    #pragma unroll
    for (int k = 0; k < H2; ++k) {
        const float h = fmaxf(acc2[k], 0.0f);
        #pragma unroll
        for (int e = 0; e < NE; ++e)
            lg[e] = fmaf(h, W3[k * NE + e], lg[e]);
    }
    const float m  = fmaxf(lg[0], fmaxf(lg[1], lg[2]));
    const float e0 = __expf(lg[0] - m);
    const float e1 = __expf(lg[1] - m);
    const float e2 = __expf(lg[2] - m);
    const float inv = 1.0f / (e0 + e1 + e2);
    out[b * 3 + 0] = e0 * inv;
    out[b * 3 + 1] = e1 * inv;
    out[b * 3 + 2] = e2 * inv;
}

extern "C" void kernel_launch(void* const* d_in, const int* in_sizes, int n_in,
                              void* d_out, int out_size, void* d_ws, size_t ws_size,
                              hipStream_t stream) {
    const int*   x  = (const int*)d_in[0];
    const float* W1 = (const float*)d_in[1];
    const float* b1 = (const float*)d_in[2];
    const float* W2 = (const float*)d_in[3];
    const float* b2 = (const float*)d_in[4];
    const float* W3 = (const float*)d_in[5];
    const float* b3 = (const float*)d_in[6];
    float* out = (float*)d_out;

    const int B = in_sizes[0] / TLEN;   // 65536
    gating_fused<<<B / 256, 256, 0, stream>>>(x, W1, b1, W2, b2, W3, b3, out);
}

// Round 3
// 41.637 us; speedup vs baseline: 2.2573x; 2.2573x over previous
//
#include <hip/hip_runtime.h>

#define NBINS 40
#define TLEN  200
#define H1    128
#define H2    64

// 4 threads/sample: 64 samples per 256-thread block, grid = B/64 = 1024 blocks
// -> 4 waves/SIMD (vs 1 before). MLP is N-split across the 4 WAVES so weight
// indices stay wave-uniform -> s_load (SGPR broadcast), not per-lane loads.
__global__ __launch_bounds__(256, 4)
void gating_fused(const int* __restrict__ x,
                  const float* __restrict__ W1, const float* __restrict__ b1,
                  const float* __restrict__ W2, const float* __restrict__ b2,
                  const float* __restrict__ W3, const float* __restrict__ b3,
                  float* __restrict__ out)
{
    // feature tile: bf16 bits, row = 50 halves = 25 words (odd stride mod 32 ->
    // conflict-free u16 column reads). Reused as logit-partial buffer later.
    __shared__ __align__(16) unsigned short feath[64][50];   // 6400 B
    __shared__ float h1t[H1][65];                            // transposed h1, +1 pad: 33280 B
    float* lbuff = (float*)&feath[0][0];                     // [4][64][4] fp32 (4096 B), after barrier

    const int tid  = threadIdx.x;
    const int lane = tid & 63;
    const int w    = __builtin_amdgcn_readfirstlane(tid >> 6);  // wave id, forced uniform

    // ================= histogram: 4 threads per sample =================
    const int sub   = tid & 3;
    const int s_loc = tid >> 2;                       // block-local sample 0..63
    const long srow = (long)blockIdx.x * 64 + s_loc;

    uint32_t plo[6] = {0,0,0,0,0,0}, phi[6] = {0,0,0,0,0,0};
    const int4* xr = (const int4*)(x + srow * TLEN);
    const int nm = (sub < 2) ? 13 : 12;               // 50 int4 chunks split 13/13/12/12

    int4 cur = xr[sub];
    for (int m = 0; m < nm; ++m) {
        const int nidx = (m + 1 < nm) ? (sub + 4 * (m + 1)) : sub;
        const int4 nxt = xr[nidx];                    // prefetch next chunk
        #define PROC(T) { \
            const int t_ = (T); \
            const uint32_t sh_ = 1u << (t_ & 31); \
            uint32_t lo_ = ((uint32_t)(t_ - 1) < 31u) ? sh_ : 0u; \
            uint32_t hi_ = (t_ >= 32) ? sh_ : 0u; \
            _Pragma("unroll") \
            for (int p = 0; p < 5; ++p) { \
                const uint32_t cl = plo[p] & lo_; plo[p] ^= lo_; lo_ = cl; \
                const uint32_t ch = phi[p] & hi_; phi[p] ^= hi_; hi_ = ch; } \
            plo[5] ^= lo_; phi[5] ^= hi_; }
        PROC(cur.x) PROC(cur.y) PROC(cur.z) PROC(cur.w)
        #undef PROC
        cur = nxt;
    }

    // extract per-bin counts, all-reduce over the 4 sub-threads, pack bf16
    uint32_t pw[21];
    #pragma unroll
    for (int j = 0; j < 21; ++j) pw[j] = 0u;
    uint32_t total = 0u, uniq = 0u;
    #pragma unroll
    for (int c = 1; c < NBINS; ++c) {
        uint32_t cnt = 0u;
        #pragma unroll
        for (int p = 5; p >= 0; --p) {
            const uint32_t bit = (c < 32) ? ((plo[p] >> c) & 1u)
                                          : ((phi[p] >> (c - 32)) & 1u);
            cnt = cnt * 2u + bit;
        }
        cnt += __shfl_xor(cnt, 1);
        cnt += __shfl_xor(cnt, 2);
        total += cnt;
        uniq  += (cnt != 0u) ? 1u : 0u;
        const uint32_t bits = __float_as_uint((float)cnt) >> 16;   // exact: cnt <= 200
        const int fi = 2 + c;
        pw[fi >> 1] |= bits << ((fi & 1) * 16);
    }
    pw[0] = (__float_as_uint((float)total) >> 16)
          | ((__float_as_uint((float)uniq)  >> 16) << 16);
    // pw[1] low half = char_freq[0] = 0 (pad bin), stays 0

    if (sub == 0) {
        uint32_t* dst = (uint32_t*)&feath[s_loc][0];   // row base 100 B, 4-aligned
        #pragma unroll
        for (int j = 0; j < 21; ++j) dst[j] = pw[j];
    }
    __syncthreads();

    // ================= MLP: sample per LANE, N-split across WAVES ==========
    // layer1: wave w computes h1[w*32 .. w*32+32) for sample `lane`
    const int w32 = w * 32;
    float a[32];
    #pragma unroll
    for (int u = 0; u < 32; ++u) a[u] = b1[w32 + u];
    for (int i = 0; i < 42; ++i) {                     // runtime i: ds_read_u16 + uniform s_load
        const uint32_t us = (uint32_t)feath[lane][i];
        const float fi = __uint_as_float(us << 16);
        #pragma unroll
        for (int u = 0; u < 32; ++u)
            a[u] = fmaf(fi, W1[i * H1 + w32 + u], a[u]);
    }
    #pragma unroll
    for (int u = 0; u < 32; ++u)
        h1t[w32 + u][lane] = fmaxf(a[u], 0.0f);        // bank = (r+lane)&31: conflict-free
    __syncthreads();

    // layer2: wave w computes h2[w*16 .. w*16+16), full K=128
    const int w16 = w * 16;
    float acc[16];
    #pragma unroll
    for (int n = 0; n < 16; ++n) acc[n] = b2[w16 + n];
    for (int i = 0; i < H1; ++i) {
        const float hv = h1t[i][lane];                 // bank (i+lane)&31: conflict-free
        #pragma unroll
        for (int n = 0; n < 16; ++n)
            acc[n] = fmaf(hv, W2[i * H2 + w16 + n], acc[n]);
    }

    // layer3 partial over this wave's h2 chunk
    float lg[3];
    #pragma unroll
    for (int e = 0; e < 3; ++e) lg[e] = (w == 0) ? b3[e] : 0.0f;
    #pragma unroll
    for (int n = 0; n < 16; ++n) {
        const float hk = fmaxf(acc[n], 0.0f);
        #pragma unroll
        for (int e = 0; e < 3; ++e)
            lg[e] = fmaf(hk, W3[(w16 + n) * 3 + e], lg[e]);
    }
    // feath reads all finished before the previous barrier -> safe to reuse
    #pragma unroll
    for (int e = 0; e < 3; ++e)
        lbuff[(w * 64 + lane) * 4 + e] = lg[e];
    __syncthreads();

    // reduce partial logits across 4 waves, softmax, store
    float l0 = 0.f, l1 = 0.f, l2 = 0.f;
    #pragma unroll
    for (int wq = 0; wq < 4; ++wq) {
        l0 += lbuff[(wq * 64 + lane) * 4 + 0];
        l1 += lbuff[(wq * 64 + lane) * 4 + 1];
        l2 += lbuff[(wq * 64 + lane) * 4 + 2];
    }
    const float mx  = fmaxf(l0, fmaxf(l1, l2));
    const float e0  = __expf(l0 - mx), e1 = __expf(l1 - mx), e2 = __expf(l2 - mx);
    const float inv = 1.0f / (e0 + e1 + e2);
    if (w < 3) {                                       // waves 0..2 store one component each
        const long gs = (long)blockIdx.x * 64 + lane;
        const float v = (w == 0) ? e0 * inv : (w == 1) ? e1 * inv : e2 * inv;
        out[gs * 3 + w] = v;
    }
}

extern "C" void kernel_launch(void* const* d_in, const int* in_sizes, int n_in,
                              void* d_out, int out_size, void* d_ws, size_t ws_size,
                              hipStream_t stream) {
    const int*   x  = (const int*)d_in[0];
    const float* W1 = (const float*)d_in[1];
    const float* b1 = (const float*)d_in[2];
    const float* W2 = (const float*)d_in[3];
    const float* b2 = (const float*)d_in[4];
    const float* W3 = (const float*)d_in[5];
    const float* b3 = (const float*)d_in[6];
    float* out = (float*)d_out;

    const int B = in_sizes[0] / TLEN;   // 65536
    gating_fused<<<B / 64, 256, 0, stream>>>(x, W1, b1, W2, b2, W3, b3, out);
}

// Round 4
// 31.233 us; speedup vs baseline: 3.0093x; 1.3331x over previous
//
#include <hip/hip_runtime.h>

#define NBINS 40
#define TLEN  200
#define H1    128
#define H2    64

typedef __attribute__((ext_vector_type(8))) short bf16x8;   // 8 bf16 = 4 VGPRs
typedef __attribute__((ext_vector_type(4))) float f32x4;    // MFMA accum

__device__ __forceinline__ unsigned rtn_bf16(float v) {     // fp32 -> bf16 bits, RTN
    unsigned u = __float_as_uint(v);
    return (u + 0x7FFFu + ((u >> 16) & 1u)) >> 16;
}

// 64 samples/block, 256 threads (4 waves), grid = B/64 = 1024.
// Hist: 4 threads/sample register bitplanes (R3-proven). MLP: mfma_f32_16x16x32_bf16
// with hi/lo weight+activation splits for fp32-grade accuracy. W fragments live in
// registers (loaded from global before hist -> latency hidden). LDS 44KB -> 3 blk/CU.
__global__ __launch_bounds__(256, 3)
void gating_fused(const int* __restrict__ x,
                  const float* __restrict__ W1, const float* __restrict__ b1,
                  const float* __restrict__ W2, const float* __restrict__ b2,
                  const float* __restrict__ W3, const float* __restrict__ b3,
                  float* __restrict__ out)
{
    // stride 72 halves (36 words = 4 mod 32) -> frag b128 reads spread 8 lanes/bank-group
    __shared__ unsigned short feath[64][72];    // bf16 feature bits [sample][k], k<64 used
    __shared__ unsigned short h1hi[64][136];    // h1 hi bf16 (stride 68 words = 4 mod 32)
    __shared__ unsigned short h1lo[64][136];    // h1 lo bf16
    float* lbuf = (float*)&feath[0][0];         // [4][64][4] logit partials (after B2)
    float* h2s  = (float*)&h1lo[0][0];          // [64][67] fp32 relu(h2)   (after B3)

    const int tid  = threadIdx.x;
    const int lane = tid & 63;
    const int w    = __builtin_amdgcn_readfirstlane(tid >> 6);
    const int r    = lane & 15;
    const int g    = lane >> 4;

    // ---------- preload W fragments (registers, hi/lo bf16 split) ----------
    // B-frag layout: lane holds B[k = s*32 + g*8 + i][col = chunk + r], k-contig 8.
    bf16x8 w1h[2][2], w1l[2][2];                // [n][s], cols w*32+n*16+r, K=48 pad 64
    #pragma unroll
    for (int n = 0; n < 2; ++n)
        #pragma unroll
        for (int s = 0; s < 2; ++s) {
            const int col = w * 32 + n * 16 + r;
            #pragma unroll
            for (int i = 0; i < 8; ++i) {
                const int k = s * 32 + g * 8 + i;
                const float v = (k < 42) ? W1[k * H1 + col] : 0.0f;
                const unsigned hb = rtn_bf16(v);
                const unsigned lb = rtn_bf16(v - __uint_as_float(hb << 16));
                w1h[n][s][i] = (short)hb;
                w1l[n][s][i] = (short)lb;
            }
        }
    bf16x8 w2h[4], w2l[4];                      // [s], cols w*16+r, K=128
    #pragma unroll
    for (int s = 0; s < 4; ++s) {
        const int col = w * 16 + r;
        #pragma unroll
        for (int i = 0; i < 8; ++i) {
            const int k = s * 32 + g * 8 + i;
            const float v = W2[k * H2 + col];
            const unsigned hb = rtn_bf16(v);
            const unsigned lb = rtn_bf16(v - __uint_as_float(hb << 16));
            w2h[s][i] = (short)hb;
            w2l[s][i] = (short)lb;
        }
    }
    float b1v[2];
    b1v[0] = b1[w * 32 + r];
    b1v[1] = b1[w * 32 + 16 + r];
    const float b2v = b2[w * 16 + r];

    // ================= histogram: 4 threads/sample, 6-bit planes =================
    const int sub   = tid & 3;
    const int s_loc = tid >> 2;
    const long srow = (long)blockIdx.x * 64 + s_loc;

    uint32_t plo[6] = {0,0,0,0,0,0}, phi[6] = {0,0,0,0,0,0};
    const int4* xr = (const int4*)(x + srow * TLEN);
    const int nm = (sub < 2) ? 13 : 12;

    int4 cur = xr[sub];
    for (int m = 0; m < nm; ++m) {
        const int nidx = (m + 1 < nm) ? (sub + 4 * (m + 1)) : sub;
        const int4 nxt = xr[nidx];
        #define PROC(T) { \
            const int t_ = (T); \
            const uint32_t sh_ = 1u << (t_ & 31); \
            uint32_t lo_ = ((uint32_t)(t_ - 1) < 31u) ? sh_ : 0u; \
            uint32_t hi_ = (t_ >= 32) ? sh_ : 0u; \
            _Pragma("unroll") \
            for (int p = 0; p < 5; ++p) { \
                const uint32_t cl = plo[p] & lo_; plo[p] ^= lo_; lo_ = cl; \
                const uint32_t ch = phi[p] & hi_; phi[p] ^= hi_; hi_ = ch; } \
            plo[5] ^= lo_; phi[5] ^= hi_; }
        PROC(cur.x) PROC(cur.y) PROC(cur.z) PROC(cur.w)
        #undef PROC
        cur = nxt;
    }

    uint32_t pw[21];
    #pragma unroll
    for (int j = 0; j < 21; ++j) pw[j] = 0u;
    uint32_t total = 0u, uniq = 0u;
    #pragma unroll
    for (int c = 1; c < NBINS; ++c) {
        uint32_t cnt = 0u;
        #pragma unroll
        for (int p = 5; p >= 0; --p) {
            const uint32_t bit = (c < 32) ? ((plo[p] >> c) & 1u)
                                          : ((phi[p] >> (c - 32)) & 1u);
            cnt = cnt * 2u + bit;
        }
        cnt += __shfl_xor(cnt, 1);
        cnt += __shfl_xor(cnt, 2);
        total += cnt;
        uniq  += (cnt != 0u) ? 1u : 0u;
        const uint32_t bits = __float_as_uint((float)cnt) >> 16;  // exact (int <= 200)
        const int fi = 2 + c;
        pw[fi >> 1] |= bits << ((fi & 1) * 16);
    }
    pw[0] = (__float_as_uint((float)total) >> 16)
          | ((__float_as_uint((float)uniq)  >> 16) << 16);

    if (sub == 0) {
        uint32_t* dst = (uint32_t*)&feath[s_loc][0];
        #pragma unroll
        for (int j = 0; j < 21; ++j) dst[j] = pw[j];
        #pragma unroll
        for (int j = 21; j < 32; ++j) dst[j] = 0u;   // zero-pad k=42..63
    }
    __syncthreads();                                  // B1

    // ================= layer1: C1[64x128] = feat[64x48] @ W1, N-split by wave ====
    f32x4 acc1[4][2];
    #pragma unroll
    for (int m = 0; m < 4; ++m)
        #pragma unroll
        for (int n = 0; n < 2; ++n)
            acc1[m][n] = (f32x4){b1v[n], b1v[n], b1v[n], b1v[n]};

    #pragma unroll
    for (int s = 0; s < 2; ++s)
        #pragma unroll
        for (int m = 0; m < 4; ++m) {
            const bf16x8 af = *(const bf16x8*)&feath[m * 16 + r][s * 32 + g * 8];
            #pragma unroll
            for (int n = 0; n < 2; ++n) {
                acc1[m][n] = __builtin_amdgcn_mfma_f32_16x16x32_bf16(af, w1h[n][s], acc1[m][n], 0, 0, 0);
                acc1[m][n] = __builtin_amdgcn_mfma_f32_16x16x32_bf16(af, w1l[n][s], acc1[m][n], 0, 0, 0);
            }
        }

    // relu + hi/lo split -> LDS (C/D layout: col=lane&15, row=(lane>>4)*4+reg)
    #pragma unroll
    for (int m = 0; m < 4; ++m)
        #pragma unroll
        for (int n = 0; n < 2; ++n)
            #pragma unroll
            for (int j = 0; j < 4; ++j) {
                const float hv = fmaxf(acc1[m][n][j], 0.0f);
                const unsigned hb = rtn_bf16(hv);
                const unsigned lb = rtn_bf16(hv - __uint_as_float(hb << 16));
                const int row = m * 16 + g * 4 + j;
                const int col = w * 32 + n * 16 + r;
                h1hi[row][col] = (unsigned short)hb;
                h1lo[row][col] = (unsigned short)lb;
            }
    __syncthreads();                                  // B2

    // ================= layer2: C2[64x64] = h1[64x128] @ W2, 3-pass hi/lo ========
    f32x4 acc2[4];
    #pragma unroll
    for (int m = 0; m < 4; ++m) acc2[m] = (f32x4){b2v, b2v, b2v, b2v};

    #pragma unroll
    for (int s = 0; s < 4; ++s)
        #pragma unroll
        for (int m = 0; m < 4; ++m) {
            const int row = m * 16 + r;
            const int kh  = s * 32 + g * 8;
            const bf16x8 ah = *(const bf16x8*)&h1hi[row][kh];
            const bf16x8 al = *(const bf16x8*)&h1lo[row][kh];
            acc2[m] = __builtin_amdgcn_mfma_f32_16x16x32_bf16(ah, w2h[s], acc2[m], 0, 0, 0);
            acc2[m] = __builtin_amdgcn_mfma_f32_16x16x32_bf16(al, w2h[s], acc2[m], 0, 0, 0);
            acc2[m] = __builtin_amdgcn_mfma_f32_16x16x32_bf16(ah, w2l[s], acc2[m], 0, 0, 0);
        }
    __syncthreads();                                  // B3: all h1 reads done

    // relu(h2) -> fp32 LDS (overlays h1lo; stride 67 words, odd -> spread banks)
    #pragma unroll
    for (int m = 0; m < 4; ++m)
        #pragma unroll
        for (int j = 0; j < 4; ++j) {
            const int row = m * 16 + g * 4 + j;
            h2s[row * 67 + w * 16 + r] = fmaxf(acc2[m][j], 0.0f);
        }
    __syncthreads();                                  // B4

    // ================= layer3 partials: sample per lane, K-split by wave ========
    float lg0 = 0.f, lg1 = 0.f, lg2 = 0.f;
    for (int kk = 0; kk < 16; ++kk) {                 // uniform W3 idx -> s_load
        const float hv = h2s[lane * 67 + w * 16 + kk];
        const int wr = (w * 16 + kk) * 3;
        lg0 = fmaf(hv, W3[wr + 0], lg0);
        lg1 = fmaf(hv, W3[wr + 1], lg1);
        lg2 = fmaf(hv, W3[wr + 2], lg2);
    }
    lbuf[(w * 64 + lane) * 4 + 0] = lg0;
    lbuf[(w * 64 + lane) * 4 + 1] = lg1;
    lbuf[(w * 64 + lane) * 4 + 2] = lg2;
    __syncthreads();                                  // B5

    // ================= reduce, softmax, store ===================================
    float l0 = b3[0], l1 = b3[1], l2 = b3[2];
    #pragma unroll
    for (int wq = 0; wq < 4; ++wq) {
        l0 += lbuf[(wq * 64 + lane) * 4 + 0];
        l1 += lbuf[(wq * 64 + lane) * 4 + 1];
        l2 += lbuf[(wq * 64 + lane) * 4 + 2];
    }
    const float mx  = fmaxf(l0, fmaxf(l1, l2));
    const float e0  = __expf(l0 - mx), e1 = __expf(l1 - mx), e2 = __expf(l2 - mx);
    const float inv = 1.0f / (e0 + e1 + e2);
    if (w < 3) {
        const long gs = (long)blockIdx.x * 64 + lane;
        const float v = (w == 0) ? e0 * inv : (w == 1) ? e1 * inv : e2 * inv;
        out[gs * 3 + w] = v;
    }
}

extern "C" void kernel_launch(void* const* d_in, const int* in_sizes, int n_in,
                              void* d_out, int out_size, void* d_ws, size_t ws_size,
                              hipStream_t stream) {
    const int*   x  = (const int*)d_in[0];
    const float* W1 = (const float*)d_in[1];
    const float* b1 = (const float*)d_in[2];
    const float* W2 = (const float*)d_in[3];
    const float* b2 = (const float*)d_in[4];
    const float* W3 = (const float*)d_in[5];
    const float* b3 = (const float*)d_in[6];
    float* out = (float*)d_out;

    const int B = in_sizes[0] / TLEN;   // 65536
    gating_fused<<<B / 64, 256, 0, stream>>>(x, W1, b1, W2, b2, W3, b3, out);
}

// Round 5
// 26.727 us; speedup vs baseline: 3.5166x; 1.1686x over previous
//
#include <hip/hip_runtime.h>

#define TLEN  200
#define H1    128
#define H2    64

typedef __attribute__((ext_vector_type(8))) short bf16x8;
typedef __attribute__((ext_vector_type(4))) float f32x4;

union Frag { unsigned u[4]; bf16x8 v; };

// pack two fp32 into (hi-pair, lo-pair) of bf16 bits: hi = truncate, lo = residual
__device__ __forceinline__ void split2(float v0, float v1, unsigned& hi, unsigned& lo) {
    const unsigned u0 = __float_as_uint(v0), u1 = __float_as_uint(v1);
    hi = __builtin_amdgcn_perm(u1, u0, 0x07060302);          // {u1.hi16, u0.hi16}
    const float d0 = v0 - __uint_as_float(u0 & 0xFFFF0000u);
    const float d1 = v1 - __uint_as_float(u1 & 0xFFFF0000u);
    lo = __builtin_amdgcn_perm(__float_as_uint(d1), __float_as_uint(d0), 0x07060302);
}

// bit-sliced accumulator += a + b (two one-hot u32), 6 planes
__device__ __forceinline__ void csa_add(uint32_t p[6], uint32_t a, uint32_t b) {
    const uint32_t t = a ^ b;
    uint32_t c = (a & b) | (p[0] & t);
    p[0] ^= t;
    uint32_t cn;
    cn = p[1] & c; p[1] ^= c; c = cn;
    cn = p[2] & c; p[2] ^= c; c = cn;
    cn = p[3] & c; p[3] ^= c; c = cn;
    cn = p[4] & c; p[4] ^= c; c = cn;
    p[5] ^= c;
}

// 64 samples/block, 4 waves. LDS overlay keeps footprint at 34816 B -> 4 blocks/CU.
__global__ __launch_bounds__(256, 4)
void gating_fused(const int* __restrict__ x,
                  const float* __restrict__ W1, const float* __restrict__ b1,
                  const float* __restrict__ W2, const float* __restrict__ b2,
                  const float* __restrict__ W3, const float* __restrict__ b3,
                  float* __restrict__ out)
{
    // overlay plan (34816 B):
    //   phase A (hist -> L1):  feath[64][72] u16 @ 0       (9216 B; rows 144 B, 16B-aligned)
    //   phase B (L1 -> L2):    h1hi[64][136] @ 0 (17408), h1lo @ 17408 (17408)
    //   phase C (L2 -> L3):    h2s[64][67] f32 @ 0         (17152)
    //   phase D (L3 -> end):   lbuf[4][64][4] f32 @ 17408  (4096)
    __shared__ __align__(16) unsigned char raw[34816];
    unsigned short (*feath)[72] = (unsigned short (*)[72])raw;
    unsigned short (*h1hi)[136] = (unsigned short (*)[136])raw;
    unsigned short (*h1lo)[136] = (unsigned short (*)[136])(raw + 17408);
    float* h2s  = (float*)raw;
    float* lbuf = (float*)(raw + 17408);

    const int tid  = threadIdx.x;
    const int lane = tid & 63;
    const int w    = __builtin_amdgcn_readfirstlane(tid >> 6);
    const int r    = lane & 15;
    const int g    = lane >> 4;

    // ---------- W fragments in registers (trunc hi + residual lo bf16) ----------
    Frag w1h[2][2], w1l[2][2], w2h[4], w2l[4];
    #pragma unroll
    for (int n = 0; n < 2; ++n)
        #pragma unroll
        for (int s = 0; s < 2; ++s) {
            const int col = w * 32 + n * 16 + r;
            #pragma unroll
            for (int j = 0; j < 4; ++j) {
                const int k = s * 32 + g * 8 + j * 2;
                const float v0 = (k     < 42) ? W1[k * H1 + col]       : 0.0f;
                const float v1 = (k + 1 < 42) ? W1[(k + 1) * H1 + col] : 0.0f;
                split2(v0, v1, w1h[n][s].u[j], w1l[n][s].u[j]);
            }
        }
    #pragma unroll
    for (int s = 0; s < 4; ++s) {
        const int col = w * 16 + r;
        #pragma unroll
        for (int j = 0; j < 4; ++j) {
            const int k = s * 32 + g * 8 + j * 2;
            split2(W2[k * H2 + col], W2[(k + 1) * H2 + col], w2h[s].u[j], w2l[s].u[j]);
        }
    }
    float b1v[2];
    b1v[0] = b1[w * 32 + r];
    b1v[1] = b1[w * 32 + 16 + r];
    const float b2v = b2[w * 16 + r];

    // ================= histogram: 4 subs/sample, 1-instr one-hot + pair CSA =====
    const int sub   = tid & 3;
    const int s_loc = tid >> 2;
    const long srow = (long)blockIdx.x * 64 + s_loc;

    uint32_t plo[6] = {0,0,0,0,0,0}, phi[6] = {0,0,0,0,0,0};
    const int4* xr = (const int4*)(x + srow * TLEN);
    const int nm = (sub < 2) ? 13 : 12;

    int4 cur = xr[sub];
    for (int m = 0; m < nm; ++m) {
        const int nidx = (m + 1 < nm) ? (sub + 4 * (m + 1)) : sub;
        const int4 nxt = xr[nidx];
        {   // pad token 0 lands in plane bit 0 -> never extracted (bin 0 skipped)
            const uint64_t oa = 1ull << (cur.x & 63);
            const uint64_t ob = 1ull << (cur.y & 63);
            csa_add(plo, (uint32_t)oa, (uint32_t)ob);
            csa_add(phi, (uint32_t)(oa >> 32), (uint32_t)(ob >> 32));
        }
        {
            const uint64_t oa = 1ull << (cur.z & 63);
            const uint64_t ob = 1ull << (cur.w & 63);
            csa_add(plo, (uint32_t)oa, (uint32_t)ob);
            csa_add(phi, (uint32_t)(oa >> 32), (uint32_t)(ob >> 32));
        }
        cur = nxt;
    }

    // ---- merge planes across the 4 subs (bit-sliced vector adds via shfl) ----
    uint32_t alo[8], ahi[8];
    {
        uint32_t c = 0;
        #pragma unroll
        for (int p = 0; p < 6; ++p) {
            const uint32_t q = __shfl_xor(plo[p], 1);
            const uint32_t t = plo[p] ^ q;
            alo[p] = t ^ c;
            c = (plo[p] & q) | (t & c);
        }
        alo[6] = c;
        c = 0;
        #pragma unroll
        for (int p = 0; p < 6; ++p) {
            const uint32_t q = __shfl_xor(phi[p], 1);
            const uint32_t t = phi[p] ^ q;
            ahi[p] = t ^ c;
            c = (phi[p] & q) | (t & c);
        }
        ahi[6] = c;
        c = 0;
        #pragma unroll
        for (int p = 0; p < 7; ++p) {
            const uint32_t q = __shfl_xor(alo[p], 2);
            const uint32_t t = alo[p] ^ q;
            const uint32_t cn = (alo[p] & q) | (t & c);
            alo[p] = t ^ c;
            c = cn;
        }
        alo[7] = c;
        c = 0;
        #pragma unroll
        for (int p = 0; p < 7; ++p) {
            const uint32_t q = __shfl_xor(ahi[p], 2);
            const uint32_t t = ahi[p] ^ q;
            const uint32_t cn = (ahi[p] & q) | (t & c);
            ahi[p] = t ^ c;
            c = cn;
        }
        ahi[7] = c;
    }

    // ---- extraction: sub s owns a bin slice; bins 1..11 / 12..21 / 22..31 / 32..39
    uint32_t P[8];
    #pragma unroll
    for (int p = 0; p < 8; ++p) P[p] = (sub == 3) ? ahi[p] : alo[p];
    const int nb   = (sub == 0) ? 11 : (sub == 3) ? 8 : 10;
    const int base = (sub == 0) ? 1 : (sub == 1) ? 12 : (sub == 2) ? 22 : 0;
    const int coff = (sub == 3) ? 32 : 0;

    uint32_t tot = 0u, unq = 0u;
    for (int j = 0; j < 11; ++j) {
        if (j < nb) {
            const int sh = base + j;
            uint32_t cnt = 0u;
            #pragma unroll
            for (int p = 0; p < 8; ++p) cnt += ((P[p] >> sh) & 1u) << p;
            tot += cnt;
            unq += (cnt != 0u) ? 1u : 0u;
            feath[s_loc][2 + sh + coff] =
                (unsigned short)(__float_as_uint((float)cnt) >> 16);  // exact int->bf16
        }
    }
    tot += __shfl_xor(tot, 1); tot += __shfl_xor(tot, 2);
    unq += __shfl_xor(unq, 1); unq += __shfl_xor(unq, 2);

    uint32_t* rw = (uint32_t*)&feath[s_loc][0];
    if (sub == 0)
        rw[0] = (__float_as_uint((float)tot) >> 16)
              | ((__float_as_uint((float)unq) >> 16) << 16);      // f[0]=seq_len, f[1]=uniq
    if (sub == 1) feath[s_loc][2] = 0;                            // char_freq[0] = 0
    #pragma unroll
    for (int rep = 0; rep < 3; ++rep) {                           // zero k = 42..63
        const int wz = 21 + rep * 4 + sub;
        if (wz <= 31) rw[wz] = 0u;
    }
    __syncthreads();                                              // B1: feat ready

    // ================= layer1: C1[64x128] = feat[64x64] @ W1 ====================
    f32x4 acc1[4][2];
    #pragma unroll
    for (int m = 0; m < 4; ++m)
        #pragma unroll
        for (int n = 0; n < 2; ++n)
            acc1[m][n] = (f32x4){b1v[n], b1v[n], b1v[n], b1v[n]};

    #pragma unroll
    for (int s = 0; s < 2; ++s)
        #pragma unroll
        for (int m = 0; m < 4; ++m) {
            const bf16x8 af = *(const bf16x8*)&feath[m * 16 + r][s * 32 + g * 8];
            #pragma unroll
            for (int n = 0; n < 2; ++n) {
                acc1[m][n] = __builtin_amdgcn_mfma_f32_16x16x32_bf16(af, w1h[n][s].v, acc1[m][n], 0, 0, 0);
                acc1[m][n] = __builtin_amdgcn_mfma_f32_16x16x32_bf16(af, w1l[n][s].v, acc1[m][n], 0, 0, 0);
            }
        }
    __syncthreads();                          // B2: feath reads done (h1 overlays it)

    // relu + trunc hi/lo split -> LDS (C/D: col=lane&15, row=(lane>>4)*4+reg)
    #pragma unroll
    for (int m = 0; m < 4; ++m)
        #pragma unroll
        for (int n = 0; n < 2; ++n)
            #pragma unroll
            for (int j = 0; j < 4; ++j) {
                const float hv = fmaxf(acc1[m][n][j], 0.0f);
                const unsigned ub = __float_as_uint(hv);
                const float d = hv - __uint_as_float(ub & 0xFFFF0000u);
                const int row = m * 16 + g * 4 + j;
                const int col = w * 32 + n * 16 + r;
                h1hi[row][col] = (unsigned short)(ub >> 16);
                h1lo[row][col] = (unsigned short)(__float_as_uint(d) >> 16);
            }
    __syncthreads();                          // B3: h1 ready

    // ================= layer2: C2[64x64] = h1[64x128] @ W2, 3-pass hi/lo ========
    f32x4 acc2[4];
    #pragma unroll
    for (int m = 0; m < 4; ++m) acc2[m] = (f32x4){b2v, b2v, b2v, b2v};

    #pragma unroll
    for (int s = 0; s < 4; ++s)
        #pragma unroll
        for (int m = 0; m < 4; ++m) {
            const int row = m * 16 + r;
            const int kh  = s * 32 + g * 8;
            const bf16x8 ah = *(const bf16x8*)&h1hi[row][kh];
            const bf16x8 al = *(const bf16x8*)&h1lo[row][kh];
            acc2[m] = __builtin_amdgcn_mfma_f32_16x16x32_bf16(ah, w2h[s].v, acc2[m], 0, 0, 0);
            acc2[m] = __builtin_amdgcn_mfma_f32_16x16x32_bf16(al, w2h[s].v, acc2[m], 0, 0, 0);
            acc2[m] = __builtin_amdgcn_mfma_f32_16x16x32_bf16(ah, w2l[s].v, acc2[m], 0, 0, 0);
        }
    __syncthreads();                          // B4: h1 reads done (h2s overlays h1hi)

    // relu(h2) -> fp32 LDS
    #pragma unroll
    for (int m = 0; m < 4; ++m)
        #pragma unroll
        for (int j = 0; j < 4; ++j) {
            const int row = m * 16 + g * 4 + j;
            h2s[row * 67 + w * 16 + r] = fmaxf(acc2[m][j], 0.0f);
        }
    __syncthreads();                          // B5: h2 ready

    // ================= layer3 partials: sample per lane, K-split by wave ========
    float lg0 = 0.f, lg1 = 0.f, lg2 = 0.f;
    for (int kk = 0; kk < 16; ++kk) {
        const float hv = h2s[lane * 67 + w * 16 + kk];
        const int wr = (w * 16 + kk) * 3;
        lg0 = fmaf(hv, W3[wr + 0], lg0);
        lg1 = fmaf(hv, W3[wr + 1], lg1);
        lg2 = fmaf(hv, W3[wr + 2], lg2);
    }
    lbuf[(w * 64 + lane) * 4 + 0] = lg0;
    lbuf[(w * 64 + lane) * 4 + 1] = lg1;
    lbuf[(w * 64 + lane) * 4 + 2] = lg2;
    __syncthreads();                          // B6: partials ready

    // ================= reduce, softmax, store ===================================
    float l0 = b3[0], l1 = b3[1], l2 = b3[2];
    #pragma unroll
    for (int wq = 0; wq < 4; ++wq) {
        l0 += lbuf[(wq * 64 + lane) * 4 + 0];
        l1 += lbuf[(wq * 64 + lane) * 4 + 1];
        l2 += lbuf[(wq * 64 + lane) * 4 + 2];
    }
    const float mx  = fmaxf(l0, fmaxf(l1, l2));
    const float e0  = __expf(l0 - mx), e1 = __expf(l1 - mx), e2 = __expf(l2 - mx);
    const float inv = 1.0f / (e0 + e1 + e2);
    if (w < 3) {
        const long gs = (long)blockIdx.x * 64 + lane;
        const float v = (w == 0) ? e0 * inv : (w == 1) ? e1 * inv : e2 * inv;
        out[gs * 3 + w] = v;
    }
}

extern "C" void kernel_launch(void* const* d_in, const int* in_sizes, int n_in,
                              void* d_out, int out_size, void* d_ws, size_t ws_size,
                              hipStream_t stream) {
    const int*   x  = (const int*)d_in[0];
    const float* W1 = (const float*)d_in[1];
    const float* b1 = (const float*)d_in[2];
    const float* W2 = (const float*)d_in[3];
    const float* b2 = (const float*)d_in[4];
    const float* W3 = (const float*)d_in[5];
    const float* b3 = (const float*)d_in[6];
    float* out = (float*)d_out;

    const int B = in_sizes[0] / TLEN;   // 65536
    gating_fused<<<B / 64, 256, 0, stream>>>(x, W1, b1, W2, b2, W3, b3, out);
}